// Round 1
// baseline (2721.059 us; speedup 1.0000x reference)
//
#include <hip/hip_runtime.h>
#include <math.h>

#define B_    4
#define E_    50000
#define CIN_  32
#define CO_   64
#define EPS_  1e-5f
#define NCH_  128          // stats chunks per batch
#define EPCH_ 391          // ceil(E_/NCH_)

// ------------------------------------------------------------------
// ws layout (floats):
//   [0, B*E*64)          x1  (channel-last activations; also holds fe_t
//                             [B][E][32] during the conv1 stage)
//   then 512 floats      st  (per-(b,c) sum, sumsq)  -- atomically accumulated
//   then 512 floats      mr  (per-(b,c) mean, rstd)
// y (conv output, [B][E][64]) lives in d_out.
// ------------------------------------------------------------------

// fe [B][CIN][E] -> fet [B][E][CIN]
__global__ __launch_bounds__(256) void k_transpose_in(
    const float* __restrict__ fe, float* __restrict__ fet)
{
    __shared__ float t[CIN_][65];
    const int b = blockIdx.y;
    const int e0 = blockIdx.x * 64;
    for (int idx = threadIdx.x; idx < CIN_ * 64; idx += 256) {
        int c = idx >> 6, el = idx & 63, e = e0 + el;
        t[c][el] = (e < E_) ? fe[((size_t)b * CIN_ + c) * E_ + e] : 0.f;
    }
    __syncthreads();
    for (int idx = threadIdx.x; idx < 64 * CIN_; idx += 256) {
        int el = idx >> 5, c = idx & 31, e = e0 + el;   // CIN_ == 32
        if (e < E_) fet[((size_t)b * E_ + e) * CIN_ + c] = t[c][el];
    }
}

// xt [B][E][CIN] + edge_index -> y [B][E][64]
// y[b][e][o] = bias[o] + sum_c sum_s feat_s[c] * W[o][c][s]
template<int CIN>
__global__ __launch_bounds__(256) void k_conv(
    const float* __restrict__ xt, const int* __restrict__ ei,
    const float* __restrict__ W, const float* __restrict__ bias,
    float* __restrict__ y)
{
    const int b = blockIdx.y;
    const int e = blockIdx.x * 256 + threadIdx.x;
    if (e >= E_) return;

    const int4 nb = *reinterpret_cast<const int4*>(ei + ((size_t)b * E_ + e) * 4);
    const float* xb = xt + (size_t)b * E_ * CIN;
    const float4* pe = reinterpret_cast<const float4*>(xb + (size_t)e    * CIN);
    const float4* p1 = reinterpret_cast<const float4*>(xb + (size_t)nb.x * CIN);
    const float4* p2 = reinterpret_cast<const float4*>(xb + (size_t)nb.y * CIN);
    const float4* p3 = reinterpret_cast<const float4*>(xb + (size_t)nb.z * CIN);
    const float4* p4 = reinterpret_cast<const float4*>(xb + (size_t)nb.w * CIN);

    float acc[CO_];
#pragma unroll
    for (int o = 0; o < CO_; ++o) acc[o] = 0.f;

#pragma unroll 1
    for (int c4 = 0; c4 < CIN / 4; ++c4) {
        const float4 xe = pe[c4];
        const float4 a1 = p1[c4], a2 = p2[c4], a3 = p3[c4], a4 = p4[c4];
        float f0[4], f1[4], f2[4], f3[4], f4v[4];
        f0[0]=xe.x; f1[0]=a1.x+a3.x; f2[0]=a2.x+a4.x; f3[0]=fabsf(a1.x-a3.x); f4v[0]=fabsf(a2.x-a4.x);
        f0[1]=xe.y; f1[1]=a1.y+a3.y; f2[1]=a2.y+a4.y; f3[1]=fabsf(a1.y-a3.y); f4v[1]=fabsf(a2.y-a4.y);
        f0[2]=xe.z; f1[2]=a1.z+a3.z; f2[2]=a2.z+a4.z; f3[2]=fabsf(a1.z-a3.z); f4v[2]=fabsf(a2.z-a4.z);
        f0[3]=xe.w; f1[3]=a1.w+a3.w; f2[3]=a2.w+a4.w; f3[3]=fabsf(a1.w-a3.w); f4v[3]=fabsf(a2.w-a4.w);
#pragma unroll
        for (int cc = 0; cc < 4; ++cc) {
            const float* Wc = W + (size_t)(c4 * 4 + cc) * 5;   // wave-uniform
#pragma unroll
            for (int o = 0; o < CO_; ++o) {
                const float* Wo = Wc + o * CIN * 5;
                acc[o] += f0[cc]*Wo[0] + f1[cc]*Wo[1] + f2[cc]*Wo[2]
                        + f3[cc]*Wo[3] + f4v[cc]*Wo[4];
            }
        }
    }

    float* yp = y + ((size_t)b * E_ + e) * CO_;
#pragma unroll
    for (int o = 0; o < CO_; ++o) yp[o] = acc[o] + bias[o];
}

// per-(b,c) sum / sumsq over E via chunked partial sums + atomics
__global__ __launch_bounds__(256) void k_stats(
    const float* __restrict__ y, float* __restrict__ st)
{
    const int b = blockIdx.y;
    const int chunk = blockIdx.x;
    const int ebeg = chunk * EPCH_;
    const int eend = min(ebeg + EPCH_, E_);
    const float* yb = y + (size_t)b * E_ * CO_;

    float s = 0.f, ss = 0.f;
    for (size_t i = (size_t)ebeg * CO_ + threadIdx.x; i < (size_t)eend * CO_; i += 256) {
        float v = yb[i];
        s += v; ss += v * v;
    }
    __shared__ float sm[2][256];
    sm[0][threadIdx.x] = s; sm[1][threadIdx.x] = ss;
    __syncthreads();
    if (threadIdx.x < 64) {
        int c = threadIdx.x;   // i % 64 == tid % 64 since stride 256 and ebeg*CO_ % 64 == 0
        float ts  = sm[0][c] + sm[0][c + 64] + sm[0][c + 128] + sm[0][c + 192];
        float tss = sm[1][c] + sm[1][c + 64] + sm[1][c + 128] + sm[1][c + 192];
        atomicAdd(&st[(b * CO_ + c) * 2 + 0], ts);
        atomicAdd(&st[(b * CO_ + c) * 2 + 1], tss);
    }
}

__global__ void k_finalize(const float* __restrict__ st, float* __restrict__ mr)
{
    const int i = threadIdx.x;            // 256 == B_*CO_
    float m = st[i * 2] * (1.f / E_);
    float v = st[i * 2 + 1] * (1.f / E_) - m * m;
    mr[i * 2] = m;
    mr[i * 2 + 1] = rsqrtf(v + EPS_);
}

// x1 = relu((y-m)*rs [+ x1])   (channel-last, float4 per thread)
template<bool ADD>
__global__ __launch_bounds__(256) void k_norm(
    const float* __restrict__ y, const float* __restrict__ mr,
    float* __restrict__ x1)
{
    const size_t total4 = (size_t)B_ * E_ * CO_ / 4;
    for (size_t i4 = (size_t)blockIdx.x * 256 + threadIdx.x; i4 < total4;
         i4 += (size_t)gridDim.x * 256) {
        size_t i = i4 * 4;
        int b = (int)(i / ((size_t)E_ * CO_));
        int c = (int)(i & 63);            // multiple of 4
        float4 yv = reinterpret_cast<const float4*>(y)[i4];
        const float4* mrp = reinterpret_cast<const float4*>(mr + ((size_t)b * CO_ + c) * 2);
        float4 m01 = mrp[0], m23 = mrp[1];   // (m0,rs0,m1,rs1) (m2,rs2,m3,rs3)
        float v0 = (yv.x - m01.x) * m01.y;
        float v1 = (yv.y - m01.z) * m01.w;
        float v2 = (yv.z - m23.x) * m23.y;
        float v3 = (yv.w - m23.z) * m23.w;
        if (ADD) {
            float4 xv = reinterpret_cast<const float4*>(x1)[i4];
            v0 += xv.x; v1 += xv.y; v2 += xv.z; v3 += xv.w;
        }
        float4 r;
        r.x = fmaxf(v0, 0.f); r.y = fmaxf(v1, 0.f);
        r.z = fmaxf(v2, 0.f); r.w = fmaxf(v3, 0.f);
        reinterpret_cast<float4*>(x1)[i4] = r;
    }
}

// x1 [B][E][64] -> out [B][64][E]
__global__ __launch_bounds__(256) void k_transpose_out(
    const float* __restrict__ x1, float* __restrict__ out)
{
    __shared__ float t[CO_][65];
    const int b = blockIdx.y;
    const int e0 = blockIdx.x * 64;
    for (int idx = threadIdx.x; idx < 64 * CO_; idx += 256) {
        int c = idx & 63, el = idx >> 6, e = e0 + el;
        t[c][el] = (e < E_) ? x1[((size_t)b * E_ + e) * CO_ + c] : 0.f;
    }
    __syncthreads();
    for (int idx = threadIdx.x; idx < 64 * CO_; idx += 256) {
        int el = idx & 63, c = idx >> 6, e = e0 + el;
        if (e < E_) out[((size_t)b * CO_ + c) * E_ + e] = t[c][el];
    }
}

extern "C" void kernel_launch(void* const* d_in, const int* in_sizes, int n_in,
                              void* d_out, int out_size, void* d_ws, size_t ws_size,
                              hipStream_t stream)
{
    const float* fe = (const float*)d_in[0];
    const int*   ei = (const int*)  d_in[1];
    const float* W1 = (const float*)d_in[2];
    const float* b1 = (const float*)d_in[3];
    const float* W2 = (const float*)d_in[4];
    const float* b2 = (const float*)d_in[5];

    float* y  = (float*)d_out;                       // [B][E][64] scratch, transposed at the end
    float* x1 = (float*)d_ws;                        // [B][E][64]
    float* st = x1 + (size_t)B_ * E_ * CO_;          // [B][64][2]
    float* mr = st + B_ * CO_ * 2;                   // [B][64][2]
    float* fet = x1;                                 // fe_t aliases x1 region (dead after conv1)

    const dim3 blk(256);
    const dim3 gT((E_ + 63) / 64, B_);
    const dim3 gC((E_ + 255) / 256, B_);
    const dim3 gS(NCH_, B_);

    k_transpose_in<<<gT, blk, 0, stream>>>(fe, fet);

    hipMemsetAsync(st, 0, B_ * CO_ * 2 * sizeof(float), stream);
    k_conv<CIN_><<<gC, blk, 0, stream>>>(fet, ei, W1, b1, y);
    k_stats<<<gS, blk, 0, stream>>>(y, st);
    k_finalize<<<1, 256, 0, stream>>>(st, mr);
    k_norm<false><<<2048, blk, 0, stream>>>(y, mr, x1);

    for (int i = 0; i < 2; ++i) {
        hipMemsetAsync(st, 0, B_ * CO_ * 2 * sizeof(float), stream);
        k_conv<CO_><<<gC, blk, 0, stream>>>(x1, ei, W2 + (size_t)i * CO_ * CO_ * 5,
                                            b2 + i * CO_, y);
        k_stats<<<gS, blk, 0, stream>>>(y, st);
        k_finalize<<<1, 256, 0, stream>>>(st, mr);
        k_norm<true><<<2048, blk, 0, stream>>>(y, mr, x1);
    }

    k_transpose_out<<<gT, blk, 0, stream>>>(x1, (float*)d_out);
}

// Round 2
// 613.564 us; speedup vs baseline: 4.4348x; 4.4348x over previous
//
#include <hip/hip_runtime.h>
#include <math.h>

#define B_    4
#define E_    50000
#define CIN_  32
#define CO_   64
#define EPS_  1e-5f

typedef __attribute__((ext_vector_type(8))) short  s16x8;
typedef __attribute__((ext_vector_type(4))) float  f32x4;

__device__ __forceinline__ unsigned short f2bf(float f) {
    unsigned u = __builtin_bit_cast(unsigned, f);
    u += 0x7fffu + ((u >> 16) & 1u);      // round-to-nearest-even
    return (unsigned short)(u >> 16);
}

// ------------------------------------------------------------------
// ws layout (floats):
//   [0, B*E*64)   x1 (channel-last activations; fe_t aliases it pre-conv1)
//   + 512         st (per-(b,c) sum, sumsq; atomically accumulated)
//   + 512         mr (per-(b,c) mean, rstd)
// y (conv output, [B][E][64] fp32) lives in d_out until the final transpose.
// ------------------------------------------------------------------

// fe [B][CIN][E] -> fet [B][E][CIN]
__global__ __launch_bounds__(256) void k_transpose_in(
    const float* __restrict__ fe, float* __restrict__ fet)
{
    __shared__ float t[CIN_][65];
    const int b = blockIdx.y;
    const int e0 = blockIdx.x * 64;
    for (int idx = threadIdx.x; idx < CIN_ * 64; idx += 256) {
        int c = idx >> 6, el = idx & 63, e = e0 + el;
        t[c][el] = (e < E_) ? fe[((size_t)b * CIN_ + c) * E_ + e] : 0.f;
    }
    __syncthreads();
    for (int idx = threadIdx.x; idx < 64 * CIN_; idx += 256) {
        int el = idx >> 5, c = idx & 31, e = e0 + el;   // CIN_ == 32
        if (e < E_) fet[((size_t)b * E_ + e) * CIN_ + c] = t[c][el];
    }
}

// MFMA mesh-conv: xt [B][E][C] + edge_index -> y [B][E][64], fused stats.
// GEMM view: feats[64 edges][K=5C] (bf16, LDS) x W^T[K][64] (bf16, VGPR).
// mfma_f32_16x16x32_bf16; A: lane m=l&15, k=(l>>4)*8+j (contig);
// B: lane n=l&15, k contig (B^T rows); C/D: col=l&15, row=(l>>4)*4+reg.
template<int C>
__global__ __launch_bounds__(256, 2) void k_conv_mfma(
    const float* __restrict__ xt, const int* __restrict__ ei,
    const float* __restrict__ W, const float* __restrict__ bias,
    float* __restrict__ y, float* __restrict__ st)
{
    constexpr int K  = 5 * C;                 // 160 / 320
    constexpr int KF = K / 32;                // 5 / 10 K-fragments
    constexpr int SL = ((K / 8) + 7) & ~7;    // 16B slots per feat row (mult of 8)
    constexpr int CH = C / 4;                 // channels per builder thread

    __shared__ alignas(16) unsigned short smem[64 * SL * 8];
    __shared__ float red[4][CO_][2];

    const int b  = blockIdx.y;
    const int e0 = blockIdx.x * 64;
    const int t  = threadIdx.x;
    const int w  = t >> 6;
    const int l  = t & 63;

    // ---- phase 0: stage W (fp32 [O][C][5]) -> LDS bf16 [o][k], k = s*C+c,
    //      16B slots XOR-swizzled by (o&7) ----
    constexpr int WELEM = CO_ * K;
    for (int i4 = t; i4 < WELEM / 4; i4 += 256) {
        const float4 v = reinterpret_cast<const float4*>(W)[i4];
        const float vv[4] = {v.x, v.y, v.z, v.w};
#pragma unroll
        for (int jj = 0; jj < 4; ++jj) {
            const int idx = i4 * 4 + jj;          // = (o*C + c)*5 + s
            const int o   = idx / (C * 5);
            const int rem = idx - o * (C * 5);
            const int c   = rem / 5;
            const int s   = rem - c * 5;
            const int el  = o * K + s * C + c;
            const int adr = (((el >> 3) ^ (o & 7)) << 3) | (el & 7);
            smem[adr] = f2bf(vv[jj]);
        }
    }
    __syncthreads();

    // ---- phase 1: pull B-fragments into VGPRs ----
    s16x8 bw[KF][4];
#pragma unroll
    for (int kf = 0; kf < KF; ++kf)
#pragma unroll
        for (int nf = 0; nf < 4; ++nf) {
            const int o  = nf * 16 + (l & 15);
            const int el = o * K + kf * 32 + (l >> 4) * 8;
            const int adr = (((el >> 3) ^ (o & 7)) << 3);
            bw[kf][nf] = *reinterpret_cast<const s16x8*>(smem + adr);
        }
    __syncthreads();

    // ---- phase 2: build feats [64][K] bf16 in LDS (overwrites W) ----
    {
        const int m = t >> 2;
        const int q = t & 3;
        const int e = e0 + m;
        const bool valid = e < E_;
        const float* xb = xt + (size_t)b * E_ * C;
        int4 nb;
        if (valid) nb = *reinterpret_cast<const int4*>(ei + ((size_t)b * E_ + e) * 4);
        else { nb.x = 0; nb.y = 0; nb.z = 0; nb.w = 0; }
        const float* re = xb + (size_t)e    * C;
        const float* r1 = xb + (size_t)nb.x * C;
        const float* r2 = xb + (size_t)nb.y * C;
        const float* r3 = xb + (size_t)nb.z * C;
        const float* r4 = xb + (size_t)nb.w * C;
#pragma unroll
        for (int hh = 0; hh < CH / 8; ++hh) {
            const int cb = q * CH + hh * 8;
            s16x8 fo[5];
            if (valid) {
#pragma unroll
                for (int j2 = 0; j2 < 2; ++j2) {
                    const float4 xe = *reinterpret_cast<const float4*>(re + cb + j2 * 4);
                    const float4 a1 = *reinterpret_cast<const float4*>(r1 + cb + j2 * 4);
                    const float4 a2 = *reinterpret_cast<const float4*>(r2 + cb + j2 * 4);
                    const float4 a3 = *reinterpret_cast<const float4*>(r3 + cb + j2 * 4);
                    const float4 a4 = *reinterpret_cast<const float4*>(r4 + cb + j2 * 4);
                    const float ve[4] = {xe.x, xe.y, xe.z, xe.w};
                    const float v1[4] = {a1.x, a1.y, a1.z, a1.w};
                    const float v2[4] = {a2.x, a2.y, a2.z, a2.w};
                    const float v3[4] = {a3.x, a3.y, a3.z, a3.w};
                    const float v4[4] = {a4.x, a4.y, a4.z, a4.w};
#pragma unroll
                    for (int jj = 0; jj < 4; ++jj) {
                        const int d = j2 * 4 + jj;
                        fo[0][d] = (short)f2bf(ve[jj]);
                        fo[1][d] = (short)f2bf(v1[jj] + v3[jj]);
                        fo[2][d] = (short)f2bf(v2[jj] + v4[jj]);
                        fo[3][d] = (short)f2bf(fabsf(v1[jj] - v3[jj]));
                        fo[4][d] = (short)f2bf(fabsf(v2[jj] - v4[jj]));
                    }
                }
            } else {
#pragma unroll
                for (int s = 0; s < 5; ++s)
#pragma unroll
                    for (int d = 0; d < 8; ++d) fo[s][d] = 0;
            }
#pragma unroll
            for (int s = 0; s < 5; ++s) {
                const int in_slot = (s * C + cb) >> 3;
                const int adr = (m * SL + (in_slot ^ (m & 7))) << 3;
                *reinterpret_cast<s16x8*>(smem + adr) = fo[s];
            }
        }
    }
    __syncthreads();

    // ---- phase 3: MFMA ----
    f32x4 acc[4];
#pragma unroll
    for (int nf = 0; nf < 4; ++nf) acc[nf] = f32x4{0.f, 0.f, 0.f, 0.f};

    const int ma = w * 16 + (l & 15);
#pragma unroll
    for (int kf = 0; kf < KF; ++kf) {
        const int in_slot = kf * 4 + (l >> 4);
        const int adr = (ma * SL + (in_slot ^ (ma & 7))) << 3;
        const s16x8 a = *reinterpret_cast<const s16x8*>(smem + adr);
#pragma unroll
        for (int nf = 0; nf < 4; ++nf)
            acc[nf] = __builtin_amdgcn_mfma_f32_16x16x32_bf16(a, bw[kf][nf], acc[nf], 0, 0, 0);
    }

    // ---- phase 4: epilogue — bias, store y, fused partial stats ----
    float* yb = y + ((size_t)b * E_ + e0) * CO_;
#pragma unroll
    for (int nf = 0; nf < 4; ++nf) {
        const int o = nf * 16 + (l & 15);
        const float bv = bias[o];
        float s = 0.f, ss = 0.f;
#pragma unroll
        for (int r = 0; r < 4; ++r) {
            const int m = w * 16 + (l >> 4) * 4 + r;
            const float v = acc[nf][r] + bv;
            if (e0 + m < E_) {
                yb[(size_t)m * CO_ + o] = v;
                s += v; ss += v * v;
            }
        }
        s  += __shfl_xor(s, 16);  ss += __shfl_xor(ss, 16);
        s  += __shfl_xor(s, 32);  ss += __shfl_xor(ss, 32);
        if (l < 16) { red[w][o][0] = s; red[w][o][1] = ss; }
    }
    __syncthreads();
    if (t < CO_) {
        const float s  = red[0][t][0] + red[1][t][0] + red[2][t][0] + red[3][t][0];
        const float ss = red[0][t][1] + red[1][t][1] + red[2][t][1] + red[3][t][1];
        atomicAdd(&st[(b * CO_ + t) * 2 + 0], s);
        atomicAdd(&st[(b * CO_ + t) * 2 + 1], ss);
    }
}

__global__ void k_finalize(const float* __restrict__ st, float* __restrict__ mr)
{
    const int i = threadIdx.x;            // 256 == B_*CO_
    float m = st[i * 2] * (1.f / E_);
    float v = st[i * 2 + 1] * (1.f / E_) - m * m;
    mr[i * 2] = m;
    mr[i * 2 + 1] = rsqrtf(v + EPS_);
}

// x1 = relu((y-m)*rs [+ x1])   (channel-last, float4 per thread)
template<bool ADD>
__global__ __launch_bounds__(256) void k_norm(
    const float* __restrict__ y, const float* __restrict__ mr,
    float* __restrict__ x1)
{
    const size_t total4 = (size_t)B_ * E_ * CO_ / 4;
    for (size_t i4 = (size_t)blockIdx.x * 256 + threadIdx.x; i4 < total4;
         i4 += (size_t)gridDim.x * 256) {
        size_t i = i4 * 4;
        int b = (int)(i / ((size_t)E_ * CO_));
        int c = (int)(i & 63);            // multiple of 4
        float4 yv = reinterpret_cast<const float4*>(y)[i4];
        const float4* mrp = reinterpret_cast<const float4*>(mr + ((size_t)b * CO_ + c) * 2);
        float4 m01 = mrp[0], m23 = mrp[1];
        float v0 = (yv.x - m01.x) * m01.y;
        float v1 = (yv.y - m01.z) * m01.w;
        float v2 = (yv.z - m23.x) * m23.y;
        float v3 = (yv.w - m23.z) * m23.w;
        if (ADD) {
            float4 xv = reinterpret_cast<const float4*>(x1)[i4];
            v0 += xv.x; v1 += xv.y; v2 += xv.z; v3 += xv.w;
        }
        float4 r;
        r.x = fmaxf(v0, 0.f); r.y = fmaxf(v1, 0.f);
        r.z = fmaxf(v2, 0.f); r.w = fmaxf(v3, 0.f);
        reinterpret_cast<float4*>(x1)[i4] = r;
    }
}

// x1 [B][E][64] -> out [B][64][E]
__global__ __launch_bounds__(256) void k_transpose_out(
    const float* __restrict__ x1, float* __restrict__ out)
{
    __shared__ float t[CO_][65];
    const int b = blockIdx.y;
    const int e0 = blockIdx.x * 64;
    for (int idx = threadIdx.x; idx < 64 * CO_; idx += 256) {
        int c = idx & 63, el = idx >> 6, e = e0 + el;
        t[c][el] = (e < E_) ? x1[((size_t)b * E_ + e) * CO_ + c] : 0.f;
    }
    __syncthreads();
    for (int idx = threadIdx.x; idx < 64 * CO_; idx += 256) {
        int el = idx & 63, c = idx >> 6, e = e0 + el;
        if (e < E_) out[((size_t)b * CO_ + c) * E_ + e] = t[c][el];
    }
}

extern "C" void kernel_launch(void* const* d_in, const int* in_sizes, int n_in,
                              void* d_out, int out_size, void* d_ws, size_t ws_size,
                              hipStream_t stream)
{
    const float* fe = (const float*)d_in[0];
    const int*   ei = (const int*)  d_in[1];
    const float* W1 = (const float*)d_in[2];
    const float* b1 = (const float*)d_in[3];
    const float* W2 = (const float*)d_in[4];
    const float* b2 = (const float*)d_in[5];

    float* y  = (float*)d_out;                       // [B][E][64] scratch
    float* x1 = (float*)d_ws;                        // [B][E][64]
    float* st = x1 + (size_t)B_ * E_ * CO_;          // [B][64][2]
    float* mr = st + B_ * CO_ * 2;                   // [B][64][2]
    float* fet = x1;                                 // fe_t aliases x1 (dead after conv1)

    const dim3 blk(256);
    const dim3 gT((E_ + 63) / 64, B_);
    const dim3 gC((E_ + 63) / 64, B_);

    k_transpose_in<<<gT, blk, 0, stream>>>(fe, fet);

    hipMemsetAsync(st, 0, B_ * CO_ * 2 * sizeof(float), stream);
    k_conv_mfma<CIN_><<<gC, blk, 0, stream>>>(fet, ei, W1, b1, y, st);
    k_finalize<<<1, 256, 0, stream>>>(st, mr);
    k_norm<false><<<2048, blk, 0, stream>>>(y, mr, x1);

    for (int i = 0; i < 2; ++i) {
        hipMemsetAsync(st, 0, B_ * CO_ * 2 * sizeof(float), stream);
        k_conv_mfma<CO_><<<gC, blk, 0, stream>>>(x1, ei, W2 + (size_t)i * CO_ * CO_ * 5,
                                                 b2 + i * CO_, y, st);
        k_finalize<<<1, 256, 0, stream>>>(st, mr);
        k_norm<true><<<2048, blk, 0, stream>>>(y, mr, x1);
    }

    k_transpose_out<<<gT, blk, 0, stream>>>(x1, (float*)d_out);
}

// Round 3
// 434.437 us; speedup vs baseline: 6.2634x; 1.4123x over previous
//
#include <hip/hip_runtime.h>
#include <math.h>

#define B_    4
#define E_    50000
#define CIN_  32
#define CO_   64
#define EPS_  1e-5f
#define NBLK_ 196          // conv grid.x; each block loops tiles with stride NBLK_

typedef __attribute__((ext_vector_type(8))) short  s16x8;
typedef __attribute__((ext_vector_type(4))) float  f32x4;

__device__ __forceinline__ unsigned short f2bf(float f) {
    unsigned u = __builtin_bit_cast(unsigned, f);
    u += 0x7fffu + ((u >> 16) & 1u);      // round-to-nearest-even
    return (unsigned short)(u >> 16);
}

// ------------------------------------------------------------------
// ws layout (floats):
//   [0, B*E*64)   x1 (channel-last activations; fe_t aliases it pre-conv1)
//   + 512         st (per-(b,c) sum, sumsq; atomically accumulated)
//   + 512         mr (per-(b,c) mean, rstd)
// y (conv output, [B][E][64] fp32) lives in d_out until the final transpose.
// ------------------------------------------------------------------

// fe [B][CIN][E] -> fet [B][E][CIN]
__global__ __launch_bounds__(256) void k_transpose_in(
    const float* __restrict__ fe, float* __restrict__ fet)
{
    __shared__ float t[CIN_][65];
    const int b = blockIdx.y;
    const int e0 = blockIdx.x * 64;
    for (int idx = threadIdx.x; idx < CIN_ * 64; idx += 256) {
        int c = idx >> 6, el = idx & 63, e = e0 + el;
        t[c][el] = (e < E_) ? fe[((size_t)b * CIN_ + c) * E_ + e] : 0.f;
    }
    __syncthreads();
    for (int idx = threadIdx.x; idx < 64 * CIN_; idx += 256) {
        int el = idx >> 5, c = idx & 31, e = e0 + el;   // CIN_ == 32
        if (e < E_) fet[((size_t)b * E_ + e) * CIN_ + c] = t[c][el];
    }
}

// MFMA mesh-conv: xt [B][E][C] + edge_index -> y [B][E][64], fused stats.
// GEMM view per 64-edge tile: feats[64][K=5C] (bf16, LDS) x W^T[K][64].
// Wave w owns output slice o = w*16 + (l&15) (B-frags bw[KF], 40 VGPR max).
// W staged to LDS ONCE per block; block loops tiles (stride NBLK_).
// mfma_f32_16x16x32_bf16; A: lane m=l&15, k=(l>>4)*8+j; C/D: col=l&15,
// row=(l>>4)*4+reg (verified layouts, learn_hip m89/m91).
template<int C>
__global__ __launch_bounds__(256, 3) void k_conv_mfma(
    const float* __restrict__ xt, const int* __restrict__ ei,
    const float* __restrict__ W, const float* __restrict__ bias,
    float* __restrict__ y, float* __restrict__ st)
{
    constexpr int K  = 5 * C;                 // 160 / 320
    constexpr int KF = K / 32;                // 5 / 10 K-fragments
    constexpr int SL = ((K / 8) + 7) & ~7;    // 16B slots per row (mult of 8)
    constexpr int CH = C / 4;                 // channels per builder thread
    constexpr int NT = (E_ + 63) / 64;        // 782 tiles per batch

    __shared__ alignas(16) unsigned short smem[64 * SL * 8];

    const int b = blockIdx.y;
    const int t = threadIdx.x;
    const int w = t >> 6;
    const int l = t & 63;

    // ---- phase 0 (once per block): stage W (fp32 [O][C][5]) -> LDS bf16
    //      [o][k], k = s*C+c, 16B slots XOR-swizzled by (o&7) ----
    constexpr int WELEM = CO_ * K;
    for (int i4 = t; i4 < WELEM / 4; i4 += 256) {
        const float4 v = reinterpret_cast<const float4*>(W)[i4];
        const float vv[4] = {v.x, v.y, v.z, v.w};
#pragma unroll
        for (int jj = 0; jj < 4; ++jj) {
            const int idx = i4 * 4 + jj;          // = (o*C + c)*5 + s
            const int o   = idx / (C * 5);
            const int rem = idx - o * (C * 5);
            const int c   = rem / 5;
            const int s   = rem - c * 5;
            const int el  = o * K + s * C + c;
            const int adr = (((el >> 3) ^ (o & 7)) << 3) | (el & 7);
            smem[adr] = f2bf(vv[jj]);
        }
    }
    __syncthreads();

    // ---- phase 1 (once per block): this wave's B-fragments ----
    s16x8 bw[KF];
    const int o = w * 16 + (l & 15);
#pragma unroll
    for (int kf = 0; kf < KF; ++kf) {
        const int el  = o * K + kf * 32 + (l >> 4) * 8;
        const int adr = (((el >> 3) ^ (o & 7)) << 3);
        bw[kf] = *reinterpret_cast<const s16x8*>(smem + adr);
    }
    const float bv = bias[o];
    float sacc = 0.f, ssacc = 0.f;
    __syncthreads();

    const float* xb = xt + (size_t)b * E_ * C;
    float* ybase = y + (size_t)b * E_ * CO_;

    // ---- tile loop ----
#pragma unroll 1
    for (int tt = blockIdx.x; tt < NT; tt += NBLK_) {
        const int e0 = tt * 64;

        // phase 2: build feats [64][K] bf16 in LDS (overwrites W region)
        {
            const int m = t >> 2;
            const int q = t & 3;
            const int e = e0 + m;
            const bool valid = e < E_;
            int4 nb;
            if (valid) nb = *reinterpret_cast<const int4*>(ei + ((size_t)b * E_ + e) * 4);
            else { nb.x = 0; nb.y = 0; nb.z = 0; nb.w = 0; }
            const float* re = xb + (size_t)e    * C;
            const float* r1 = xb + (size_t)nb.x * C;
            const float* r2 = xb + (size_t)nb.y * C;
            const float* r3 = xb + (size_t)nb.z * C;
            const float* r4 = xb + (size_t)nb.w * C;
#pragma unroll
            for (int hh = 0; hh < CH / 8; ++hh) {
                const int cb = q * CH + hh * 8;
                s16x8 fo[5];
                if (valid) {
#pragma unroll
                    for (int j2 = 0; j2 < 2; ++j2) {
                        const float4 xe = *reinterpret_cast<const float4*>(re + cb + j2 * 4);
                        const float4 a1 = *reinterpret_cast<const float4*>(r1 + cb + j2 * 4);
                        const float4 a2 = *reinterpret_cast<const float4*>(r2 + cb + j2 * 4);
                        const float4 a3 = *reinterpret_cast<const float4*>(r3 + cb + j2 * 4);
                        const float4 a4 = *reinterpret_cast<const float4*>(r4 + cb + j2 * 4);
                        const float ve[4] = {xe.x, xe.y, xe.z, xe.w};
                        const float v1[4] = {a1.x, a1.y, a1.z, a1.w};
                        const float v2[4] = {a2.x, a2.y, a2.z, a2.w};
                        const float v3[4] = {a3.x, a3.y, a3.z, a3.w};
                        const float v4[4] = {a4.x, a4.y, a4.z, a4.w};
#pragma unroll
                        for (int jj = 0; jj < 4; ++jj) {
                            const int d = j2 * 4 + jj;
                            fo[0][d] = (short)f2bf(ve[jj]);
                            fo[1][d] = (short)f2bf(v1[jj] + v3[jj]);
                            fo[2][d] = (short)f2bf(v2[jj] + v4[jj]);
                            fo[3][d] = (short)f2bf(fabsf(v1[jj] - v3[jj]));
                            fo[4][d] = (short)f2bf(fabsf(v2[jj] - v4[jj]));
                        }
                    }
                } else {
#pragma unroll
                    for (int s = 0; s < 5; ++s)
#pragma unroll
                        for (int d = 0; d < 8; ++d) fo[s][d] = 0;
                }
#pragma unroll
                for (int s = 0; s < 5; ++s) {
                    const int in_slot = (s * C + cb) >> 3;
                    const int adr = (m * SL + (in_slot ^ (m & 7))) << 3;
                    *reinterpret_cast<s16x8*>(smem + adr) = fo[s];
                }
            }
        }
        __syncthreads();

        // phase 3+4: MFMA over 4 M-frags + fused epilogue
        float* yb = ybase + (size_t)e0 * CO_;
#pragma unroll
        for (int mf = 0; mf < 4; ++mf) {
            f32x4 acc = f32x4{0.f, 0.f, 0.f, 0.f};
            const int ma = mf * 16 + (l & 15);
#pragma unroll
            for (int kf = 0; kf < KF; ++kf) {
                const int slot = kf * 4 + (l >> 4);
                const int adr  = (ma * SL + (slot ^ (ma & 7))) << 3;
                const s16x8 a  = *reinterpret_cast<const s16x8*>(smem + adr);
                acc = __builtin_amdgcn_mfma_f32_16x16x32_bf16(a, bw[kf], acc, 0, 0, 0);
            }
#pragma unroll
            for (int r = 0; r < 4; ++r) {
                const int m = mf * 16 + (l >> 4) * 4 + r;
                const float v = acc[r] + bv;
                if (e0 + m < E_) {
                    yb[(size_t)m * CO_ + o] = v;
                    sacc += v; ssacc += v * v;
                }
            }
        }
        __syncthreads();
    }

    // ---- block-level stats flush ----
    sacc  += __shfl_xor(sacc, 16);  ssacc += __shfl_xor(ssacc, 16);
    sacc  += __shfl_xor(sacc, 32);  ssacc += __shfl_xor(ssacc, 32);
    if (l < 16) {
        atomicAdd(&st[(b * CO_ + o) * 2 + 0], sacc);
        atomicAdd(&st[(b * CO_ + o) * 2 + 1], ssacc);
    }
}

__global__ void k_finalize(const float* __restrict__ st, float* __restrict__ mr)
{
    const int i = threadIdx.x;            // 256 == B_*CO_
    float m = st[i * 2] * (1.f / E_);
    float v = st[i * 2 + 1] * (1.f / E_) - m * m;
    mr[i * 2] = m;
    mr[i * 2 + 1] = rsqrtf(v + EPS_);
}

// x1 = relu((y-m)*rs [+ x1])   (channel-last, float4 per thread)
template<bool ADD>
__global__ __launch_bounds__(256) void k_norm(
    const float* __restrict__ y, const float* __restrict__ mr,
    float* __restrict__ x1)
{
    const size_t total4 = (size_t)B_ * E_ * CO_ / 4;
    for (size_t i4 = (size_t)blockIdx.x * 256 + threadIdx.x; i4 < total4;
         i4 += (size_t)gridDim.x * 256) {
        size_t i = i4 * 4;
        int b = (int)(i / ((size_t)E_ * CO_));
        int c = (int)(i & 63);            // multiple of 4
        float4 yv = reinterpret_cast<const float4*>(y)[i4];
        const float4* mrp = reinterpret_cast<const float4*>(mr + ((size_t)b * CO_ + c) * 2);
        float4 m01 = mrp[0], m23 = mrp[1];
        float v0 = (yv.x - m01.x) * m01.y;
        float v1 = (yv.y - m01.z) * m01.w;
        float v2 = (yv.z - m23.x) * m23.y;
        float v3 = (yv.w - m23.z) * m23.w;
        if (ADD) {
            float4 xv = reinterpret_cast<const float4*>(x1)[i4];
            v0 += xv.x; v1 += xv.y; v2 += xv.z; v3 += xv.w;
        }
        float4 r;
        r.x = fmaxf(v0, 0.f); r.y = fmaxf(v1, 0.f);
        r.z = fmaxf(v2, 0.f); r.w = fmaxf(v3, 0.f);
        reinterpret_cast<float4*>(x1)[i4] = r;
    }
}

// x1 [B][E][64] -> out [B][64][E]
__global__ __launch_bounds__(256) void k_transpose_out(
    const float* __restrict__ x1, float* __restrict__ out)
{
    __shared__ float t[CO_][65];
    const int b = blockIdx.y;
    const int e0 = blockIdx.x * 64;
    for (int idx = threadIdx.x; idx < 64 * CO_; idx += 256) {
        int c = idx & 63, el = idx >> 6, e = e0 + el;
        t[c][el] = (e < E_) ? x1[((size_t)b * E_ + e) * CO_ + c] : 0.f;
    }
    __syncthreads();
    for (int idx = threadIdx.x; idx < 64 * CO_; idx += 256) {
        int el = idx & 63, c = idx >> 6, e = e0 + el;
        if (e < E_) out[((size_t)b * CO_ + c) * E_ + e] = t[c][el];
    }
}

extern "C" void kernel_launch(void* const* d_in, const int* in_sizes, int n_in,
                              void* d_out, int out_size, void* d_ws, size_t ws_size,
                              hipStream_t stream)
{
    const float* fe = (const float*)d_in[0];
    const int*   ei = (const int*)  d_in[1];
    const float* W1 = (const float*)d_in[2];
    const float* b1 = (const float*)d_in[3];
    const float* W2 = (const float*)d_in[4];
    const float* b2 = (const float*)d_in[5];

    float* y  = (float*)d_out;                       // [B][E][64] scratch
    float* x1 = (float*)d_ws;                        // [B][E][64]
    float* st = x1 + (size_t)B_ * E_ * CO_;          // [B][64][2]
    float* mr = st + B_ * CO_ * 2;                   // [B][64][2]
    float* fet = x1;                                 // fe_t aliases x1 (dead after conv1)

    const dim3 blk(256);
    const dim3 gT((E_ + 63) / 64, B_);
    const dim3 gC(NBLK_, B_);

    k_transpose_in<<<gT, blk, 0, stream>>>(fe, fet);

    hipMemsetAsync(st, 0, B_ * CO_ * 2 * sizeof(float), stream);
    k_conv_mfma<CIN_><<<gC, blk, 0, stream>>>(fet, ei, W1, b1, y, st);
    k_finalize<<<1, 256, 0, stream>>>(st, mr);
    k_norm<false><<<2048, blk, 0, stream>>>(y, mr, x1);

    for (int i = 0; i < 2; ++i) {
        hipMemsetAsync(st, 0, B_ * CO_ * 2 * sizeof(float), stream);
        k_conv_mfma<CO_><<<gC, blk, 0, stream>>>(x1, ei, W2 + (size_t)i * CO_ * CO_ * 5,
                                                 b2 + i * CO_, y, st);
        k_finalize<<<1, 256, 0, stream>>>(st, mr);
        k_norm<true><<<2048, blk, 0, stream>>>(y, mr, x1);
    }

    k_transpose_out<<<gT, blk, 0, stream>>>(x1, (float*)d_out);
}

// Round 5
// 256.169 us; speedup vs baseline: 10.6221x; 1.6959x over previous
//
#include <hip/hip_runtime.h>
#include <math.h>

#define B_    4
#define E_    50000
#define CIN_  32
#define CO_   64
#define EPS_  1e-5f
#define NBLK_ 196                  // blocks per batch; grid = NBLK_*B_ (1-D, XCD-pinned)
#define NT_   ((E_ + 63) / 64)     // 782 tiles per batch

typedef __attribute__((ext_vector_type(8))) short  s16x8;
typedef __attribute__((ext_vector_type(4))) float  f32x4;
typedef unsigned short u16;

__device__ __forceinline__ u16 f2bf(float f) {
    unsigned u = __builtin_bit_cast(unsigned, f);
    u += 0x7fffu + ((u >> 16) & 1u);      // round-to-nearest-even
    return (u16)(u >> 16);
}
__device__ __forceinline__ float bf2f(u16 h) {
    return __builtin_bit_cast(float, (unsigned)h << 16);
}

// ------------------------------------------------------------------
// ws layout:
//   [0, B*E*64) u16   x1 (channel-last bf16; fet [B][E][32] aliases it)
//   [B*E*64, 2*B*E*64) u16  y (conv output, bf16 channel-last)
//   + 512 floats      st (per-(b,c) sum, sumsq; atomically accumulated)
// Total 51.2 MB + 2 KB (same budget as rounds 1-3).
// ------------------------------------------------------------------

// fe fp32 [B][CIN][E] -> fet bf16 [B][E][CIN]
__global__ __launch_bounds__(256) void k_transpose_in(
    const float* __restrict__ fe, u16* __restrict__ fet)
{
    __shared__ float t[CIN_][65];
    const int b = blockIdx.y;
    const int e0 = blockIdx.x * 64;
    for (int idx = threadIdx.x; idx < CIN_ * 64; idx += 256) {
        int c = idx >> 6, el = idx & 63, e = e0 + el;
        t[c][el] = (e < E_) ? fe[((size_t)b * CIN_ + c) * E_ + e] : 0.f;
    }
    __syncthreads();
    for (int idx = threadIdx.x; idx < 64 * CIN_; idx += 256) {
        int el = idx >> 5, c = idx & 31, e = e0 + el;   // CIN_ == 32
        if (e < E_) fet[((size_t)b * E_ + e) * CIN_ + c] = f2bf(t[c][el]);
    }
}

// MFMA mesh-conv, bf16 activations: xt [B][E][C] bf16 + edges -> y bf16, fused stats.
// Wave w owns o = w*16+(l&15); W staged once per block; XCD-pinned batches:
// blocks id with id&7 in {2b,2b+1} serve batch b (per-XCD L2 holds that batch's x).
// Epilogue goes through LDS ytile so global y-writes are full-line coalesced.
template<int C>
__global__ __launch_bounds__(256, 3) void k_conv_mfma(
    const u16* __restrict__ xt, const int* __restrict__ ei,
    const float* __restrict__ W, const float* __restrict__ bias,
    u16* __restrict__ y, float* __restrict__ st)
{
    constexpr int K  = 5 * C;                 // 160 / 320
    constexpr int KF = K / 32;                // 5 / 10
    constexpr int SL = ((K / 8) + 7) & ~7;    // 16B slots per feat row
    constexpr int CH = C / 4;                 // channels per builder thread
    constexpr int YP = 72;                    // padded ytile row (u16)

    __shared__ alignas(16) u16 smem[64 * SL * 8];
    __shared__ alignas(16) u16 ytile[64 * YP];

    const int id  = blockIdx.x;
    const int xcd = id & 7;
    const int b   = xcd >> 1;
    const int j   = ((id >> 3) << 1) | (xcd & 1);   // [0, NBLK_)

    const int t = threadIdx.x;
    const int w = t >> 6;
    const int l = t & 63;

    // ---- phase 0 (once): stage W fp32 [O][C][5] -> LDS bf16 [o][k], k=s*C+c,
    //      16B slots XOR-swizzled by (o&7) ----
    constexpr int WELEM = CO_ * K;
    for (int i4 = t; i4 < WELEM / 4; i4 += 256) {
        const float4 v = reinterpret_cast<const float4*>(W)[i4];
        const float vv[4] = {v.x, v.y, v.z, v.w};
#pragma unroll
        for (int jj = 0; jj < 4; ++jj) {
            const int idx = i4 * 4 + jj;          // = (o*C + c)*5 + s
            const int o   = idx / (C * 5);
            const int rem = idx - o * (C * 5);
            const int c   = rem / 5;
            const int s   = rem - c * 5;
            const int el  = o * K + s * C + c;
            const int adr = (((el >> 3) ^ (o & 7)) << 3) | (el & 7);
            smem[adr] = f2bf(vv[jj]);
        }
    }
    __syncthreads();

    // ---- phase 1 (once): this wave's B-fragments ----
    s16x8 bw[KF];
    const int o = w * 16 + (l & 15);
#pragma unroll
    for (int kf = 0; kf < KF; ++kf) {
        const int el  = o * K + kf * 32 + (l >> 4) * 8;
        const int adr = (((el >> 3) ^ (o & 7)) << 3);
        bw[kf] = *reinterpret_cast<const s16x8*>(smem + adr);
    }
    const float bv = bias[o];
    float sacc = 0.f, ssacc = 0.f;
    __syncthreads();

    const u16* xb = xt + (size_t)b * E_ * C;
    u16* ybase = y + (size_t)b * E_ * CO_;

    // ---- tile loop ----
#pragma unroll 1
    for (int tt = j; tt < NT_; tt += NBLK_) {
        const int e0 = tt * 64;

        // build feats [64][K] bf16 in LDS (overwrites W region)
        {
            const int m = t >> 2;
            const int q = t & 3;
            const int e = e0 + m;
            const bool valid = e < E_;
            int4 nb;
            if (valid) nb = *reinterpret_cast<const int4*>(ei + ((size_t)b * E_ + e) * 4);
            else { nb.x = 0; nb.y = 0; nb.z = 0; nb.w = 0; }
            const u16* re = xb + (size_t)e    * C;
            const u16* r1 = xb + (size_t)nb.x * C;
            const u16* r2 = xb + (size_t)nb.y * C;
            const u16* r3 = xb + (size_t)nb.z * C;
            const u16* r4 = xb + (size_t)nb.w * C;
#pragma unroll
            for (int hh = 0; hh < CH / 8; ++hh) {
                const int cb = q * CH + hh * 8;
                s16x8 fo[5];
                if (valid) {
                    const s16x8 xe = *reinterpret_cast<const s16x8*>(re + cb);
                    const s16x8 a1 = *reinterpret_cast<const s16x8*>(r1 + cb);
                    const s16x8 a2 = *reinterpret_cast<const s16x8*>(r2 + cb);
                    const s16x8 a3 = *reinterpret_cast<const s16x8*>(r3 + cb);
                    const s16x8 a4 = *reinterpret_cast<const s16x8*>(r4 + cb);
                    fo[0] = xe;                           // identity feat: exact copy
#pragma unroll
                    for (int d = 0; d < 8; ++d) {
                        const float v1 = bf2f((u16)a1[d]);
                        const float v2 = bf2f((u16)a2[d]);
                        const float v3 = bf2f((u16)a3[d]);
                        const float v4 = bf2f((u16)a4[d]);
                        fo[1][d] = (short)f2bf(v1 + v3);
                        fo[2][d] = (short)f2bf(v2 + v4);
                        fo[3][d] = (short)f2bf(fabsf(v1 - v3));
                        fo[4][d] = (short)f2bf(fabsf(v2 - v4));
                    }
                } else {
#pragma unroll
                    for (int s = 0; s < 5; ++s) fo[s] = s16x8{0,0,0,0,0,0,0,0};
                }
#pragma unroll
                for (int s = 0; s < 5; ++s) {
                    const int in_slot = (s * C + cb) >> 3;
                    const int adr = (m * SL + (in_slot ^ (m & 7))) << 3;
                    *reinterpret_cast<s16x8*>(smem + adr) = fo[s];
                }
            }
        }
        __syncthreads();

        // MFMA + epilogue -> LDS ytile (bf16), stats in regs
#pragma unroll
        for (int mf = 0; mf < 4; ++mf) {
            f32x4 acc = f32x4{0.f, 0.f, 0.f, 0.f};
            const int ma = mf * 16 + (l & 15);
#pragma unroll
            for (int kf = 0; kf < KF; ++kf) {
                const int slot = kf * 4 + (l >> 4);
                const int adr  = (ma * SL + (slot ^ (ma & 7))) << 3;
                const s16x8 a  = *reinterpret_cast<const s16x8*>(smem + adr);
                acc = __builtin_amdgcn_mfma_f32_16x16x32_bf16(a, bw[kf], acc, 0, 0, 0);
            }
#pragma unroll
            for (int r = 0; r < 4; ++r) {
                const int m = mf * 16 + (l >> 4) * 4 + r;
                const float v = acc[r] + bv;
                ytile[m * YP + o] = f2bf(v);
                if (e0 + m < E_) { sacc += v; ssacc += v * v; }
            }
        }
        __syncthreads();

        // coalesced store ytile -> y
        for (int idx = t; idx < 512; idx += 256) {
            const int row = idx >> 3, c8 = idx & 7;
            if (e0 + row < E_)
                *reinterpret_cast<s16x8*>(ybase + (size_t)(e0 + row) * CO_ + c8 * 8) =
                    *reinterpret_cast<const s16x8*>(ytile + row * YP + c8 * 8);
        }
        __syncthreads();
    }

    // ---- block-level stats flush ----
    sacc  += __shfl_xor(sacc, 16);  ssacc += __shfl_xor(ssacc, 16);
    sacc  += __shfl_xor(sacc, 32);  ssacc += __shfl_xor(ssacc, 32);
    if (l < 16) {
        atomicAdd(&st[(b * CO_ + o) * 2 + 0], sacc);
        atomicAdd(&st[(b * CO_ + o) * 2 + 1], ssacc);
    }
}

// x1 = relu((y-m)*rs [+ x1]); m/rs computed inline from st (bf16 I/O)
template<bool ADD>
__global__ __launch_bounds__(256) void k_norm(
    const u16* __restrict__ y, const float* __restrict__ st,
    u16* __restrict__ x1)
{
    constexpr float invE = 1.f / E_;
    const size_t total8 = (size_t)B_ * E_ * CO_ / 8;
    for (size_t i8 = (size_t)blockIdx.x * 256 + threadIdx.x; i8 < total8;
         i8 += (size_t)gridDim.x * 256) {
        const size_t i = i8 * 8;
        const int b = (int)(i / ((size_t)E_ * CO_));
        const int c = (int)(i & 63);          // multiple of 8
        const s16x8 yv = reinterpret_cast<const s16x8*>(y)[i8];
        s16x8 xv;
        if (ADD) xv = reinterpret_cast<const s16x8*>(x1)[i8];
        const float4* stp = reinterpret_cast<const float4*>(st + ((size_t)b * CO_ + c) * 2);
        s16x8 ov;
#pragma unroll
        for (int d2 = 0; d2 < 4; ++d2) {
            const float4 s2 = stp[d2];        // (sum,sumsq) x2 channels
            const float m0 = s2.x * invE, v0 = s2.y * invE - m0 * m0;
            const float m1 = s2.z * invE, v1 = s2.w * invE - m1 * m1;
            float a0 = (bf2f((u16)yv[d2*2])   - m0) * rsqrtf(v0 + EPS_);
            float a1 = (bf2f((u16)yv[d2*2+1]) - m1) * rsqrtf(v1 + EPS_);
            if (ADD) { a0 += bf2f((u16)xv[d2*2]); a1 += bf2f((u16)xv[d2*2+1]); }
            ov[d2*2]   = (short)f2bf(fmaxf(a0, 0.f));
            ov[d2*2+1] = (short)f2bf(fmaxf(a1, 0.f));
        }
        reinterpret_cast<s16x8*>(x1)[i8] = ov;
    }
}

// final block: out[b][c][e] = relu((y-m)*rs + x1)  (fused norm+residual+transpose)
__global__ __launch_bounds__(256) void k_norm_t(
    const u16* __restrict__ y, const float* __restrict__ st,
    const u16* __restrict__ x1, float* __restrict__ out)
{
    __shared__ float tt[CO_][65];
    constexpr float invE = 1.f / E_;
    const int b  = blockIdx.y;
    const int e0 = blockIdx.x * 64;
    const int t  = threadIdx.x;
    for (int idx = t; idx < 512; idx += 256) {
        const int el = idx >> 3, c = (idx & 7) * 8;
        const int e  = e0 + el;
        if (e < E_) {
            const size_t base = ((size_t)b * E_ + e) * CO_ + c;
            const s16x8 yv = *reinterpret_cast<const s16x8*>(y  + base);
            const s16x8 xv = *reinterpret_cast<const s16x8*>(x1 + base);
            const float4* stp = reinterpret_cast<const float4*>(st + ((size_t)b * CO_ + c) * 2);
#pragma unroll
            for (int d2 = 0; d2 < 4; ++d2) {
                const float4 s2 = stp[d2];
                const float m0 = s2.x * invE, v0 = s2.y * invE - m0 * m0;
                const float m1 = s2.z * invE, v1 = s2.w * invE - m1 * m1;
                const float a0 = (bf2f((u16)yv[d2*2])   - m0) * rsqrtf(v0 + EPS_) + bf2f((u16)xv[d2*2]);
                const float a1 = (bf2f((u16)yv[d2*2+1]) - m1) * rsqrtf(v1 + EPS_) + bf2f((u16)xv[d2*2+1]);
                tt[c + d2*2][el]     = fmaxf(a0, 0.f);
                tt[c + d2*2 + 1][el] = fmaxf(a1, 0.f);
            }
        }
    }
    __syncthreads();
    for (int idx = t; idx < 1024; idx += 256) {
        const int c = idx >> 4, seg = idx & 15;
        const int e = e0 + seg * 4;
        float* op = out + ((size_t)b * CO_ + c) * E_;
        if (e + 3 < E_) {
            float4 v = {tt[c][seg*4], tt[c][seg*4+1], tt[c][seg*4+2], tt[c][seg*4+3]};
            *reinterpret_cast<float4*>(op + e) = v;
        } else {
#pragma unroll
            for (int k2 = 0; k2 < 4; ++k2)
                if (e + k2 < E_) op[e + k2] = tt[c][seg*4 + k2];
        }
    }
}

extern "C" void kernel_launch(void* const* d_in, const int* in_sizes, int n_in,
                              void* d_out, int out_size, void* d_ws, size_t ws_size,
                              hipStream_t stream)
{
    const float* fe = (const float*)d_in[0];
    const int*   ei = (const int*)  d_in[1];
    const float* W1 = (const float*)d_in[2];
    const float* b1 = (const float*)d_in[3];
    const float* W2 = (const float*)d_in[4];
    const float* b2 = (const float*)d_in[5];

    u16*   x1  = (u16*)d_ws;                          // [B][E][64] bf16
    u16*   y   = x1 + (size_t)B_ * E_ * CO_;          // [B][E][64] bf16
    float* st  = (float*)(y + (size_t)B_ * E_ * CO_); // [B][64][2]
    u16*   fet = x1;                                  // fe_t aliases x1 (dead after conv1)
    float* out = (float*)d_out;

    const dim3 blk(256);
    const dim3 gT(NT_, B_);
    const dim3 gC(NBLK_ * B_);

    k_transpose_in<<<gT, blk, 0, stream>>>(fe, fet);

    hipMemsetAsync(st, 0, B_ * CO_ * 2 * sizeof(float), stream);
    k_conv_mfma<CIN_><<<gC, blk, 0, stream>>>(fet, ei, W1, b1, y, st);
    k_norm<false><<<2048, blk, 0, stream>>>(y, st, x1);

    hipMemsetAsync(st, 0, B_ * CO_ * 2 * sizeof(float), stream);
    k_conv_mfma<CO_><<<gC, blk, 0, stream>>>(x1, ei, W2, b2, y, st);
    k_norm<true><<<2048, blk, 0, stream>>>(y, st, x1);

    hipMemsetAsync(st, 0, B_ * CO_ * 2 * sizeof(float), stream);
    k_conv_mfma<CO_><<<gC, blk, 0, stream>>>(x1, ei, W2 + (size_t)CO_ * CO_ * 5,
                                             b2 + CO_, y, st);
    k_norm_t<<<gT, blk, 0, stream>>>(y, st, x1, out);
}